// Round 4
// baseline (603.514 us; speedup 1.0000x reference)
//
#include <hip/hip_runtime.h>
#include <math.h>

// Problem constants: B=8, H=W=64, C=64, CI=32, SCALE=4, PATCH=3, N=256
#define BB 8

typedef __attribute__((ext_vector_type(8))) short short8;   // 8 x bf16 bits
typedef __attribute__((ext_vector_type(4))) float f32x4;

__device__ inline short f2bf(float x) {          // fp32 -> bf16 (RNE)
  unsigned u = __builtin_bit_cast(unsigned, x);
  u += 0x7fffu + ((u >> 16) & 1u);
  return (short)(u >> 16);
}
__device__ inline float bf2f(short h) {
  unsigned u = ((unsigned)(unsigned short)h) << 16;
  return __builtin_bit_cast(float, u);
}

__device__ inline void gload_lds16(const void* g, void* l) {
  __builtin_amdgcn_global_load_lds(
      (const __attribute__((address_space(1))) void*)g,
      (__attribute__((address_space(3))) void*)l, 16, 0, 0);
}

// ---------------- K1: theta & g conv1x1 + prelu (LDS-tiled) ----------------
// grid: 8 b x 32 pixel-groups (128 px each), 256 threads.
// thread = (pixel-pair pp, quarter q): computes 2 px x (16 g-ch + 8 theta-ch).
__global__ __launch_bounds__(256) void k_theta_g(const float* __restrict__ x,
                          const float* __restrict__ theta_w, const float* __restrict__ theta_b,
                          const float* __restrict__ theta_alpha,
                          const float* __restrict__ g_w, const float* __restrict__ g_b,
                          const float* __restrict__ g_alpha,
                          short* __restrict__ thetaPh, short* __restrict__ thetaPl,
                          float* __restrict__ g) {
  int bid = blockIdx.x;
  int b = bid >> 5, pg = bid & 31;
  int px0 = pg * 128;
  int tid = threadIdx.x;
  __shared__ float gw[64 * 64];     // [k][c]
  __shared__ float tw[64 * 32];     // [k][c]
  __shared__ float xs[64 * 128];    // [k][p]  (transposed)
  __shared__ float gb_s[64], ga_s[64], tb_s[32], ta_s[32];
  for (int idx = tid; idx < 1024; idx += 256) ((float4*)gw)[idx] = ((const float4*)g_w)[idx];
  for (int idx = tid; idx < 512; idx += 256)  ((float4*)tw)[idx] = ((const float4*)theta_w)[idx];
  if (tid < 64) { gb_s[tid] = g_b[tid]; ga_s[tid] = g_alpha[tid]; }
  else if (tid < 96) { tb_s[tid - 64] = theta_b[tid - 64]; ta_s[tid - 64] = theta_alpha[tid - 64]; }
  {
    int p = tid >> 1, half = tid & 1;
    const float* xp = x + ((size_t)b * 4096 + px0 + p) * 64 + half * 32;
    #pragma unroll
    for (int i = 0; i < 8; ++i) {
      float4 v = ((const float4*)xp)[i];
      int k = half * 32 + i * 4;
      xs[(k + 0) * 128 + p] = v.x; xs[(k + 1) * 128 + p] = v.y;
      xs[(k + 2) * 128 + p] = v.z; xs[(k + 3) * 128 + p] = v.w;
    }
  }
  __syncthreads();
  int pp = tid >> 2, q = tid & 3;
  float accg[2][16], acct[2][8];
  #pragma unroll
  for (int c = 0; c < 16; ++c) { float bv = gb_s[q * 16 + c]; accg[0][c] = bv; accg[1][c] = bv; }
  #pragma unroll
  for (int c = 0; c < 8; ++c)  { float bv = tb_s[q * 8 + c];  acct[0][c] = bv; acct[1][c] = bv; }
  for (int k = 0; k < 64; ++k) {
    float x0 = xs[k * 128 + 2 * pp], x1 = xs[k * 128 + 2 * pp + 1];
    const float* gwr = gw + k * 64 + q * 16;
    const float* twr = tw + k * 32 + q * 8;
    #pragma unroll
    for (int c = 0; c < 16; ++c) { float wv = gwr[c]; accg[0][c] += x0 * wv; accg[1][c] += x1 * wv; }
    #pragma unroll
    for (int c = 0; c < 8; ++c)  { float wv = twr[c]; acct[0][c] += x0 * wv; acct[1][c] += x1 * wv; }
  }
  #pragma unroll
  for (int e = 0; e < 2; ++e) {
    int px = px0 + 2 * pp + e;
    float* gp = g + ((size_t)b * 4096 + px) * 64 + q * 16;
    #pragma unroll
    for (int c4 = 0; c4 < 4; ++c4) {
      float4 v;
      v.x = accg[e][c4*4+0]; v.y = accg[e][c4*4+1]; v.z = accg[e][c4*4+2]; v.w = accg[e][c4*4+3];
      float a0 = ga_s[q*16+c4*4+0], a1 = ga_s[q*16+c4*4+1], a2 = ga_s[q*16+c4*4+2], a3 = ga_s[q*16+c4*4+3];
      v.x = v.x >= 0.f ? v.x : a0 * v.x; v.y = v.y >= 0.f ? v.y : a1 * v.y;
      v.z = v.z >= 0.f ? v.z : a2 * v.z; v.w = v.w >= 0.f ? v.w : a3 * v.w;
      ((float4*)gp)[c4] = v;
    }
    int h = px >> 6, w = px & 63;
    size_t off = ((size_t)(b * 66 + h + 1) * 66 + (w + 1)) * 32 + q * 8;
    short8 hv, lv;
    #pragma unroll
    for (int c = 0; c < 8; ++c) {
      float t = acct[e][c];
      float a = ta_s[q * 8 + c];
      float v = t >= 0.f ? t : a * t;
      short hi = f2bf(v);
      hv[c] = hi;
      lv[c] = f2bf(v - bf2f(hi));
    }
    *(short8*)(thetaPh + off) = hv;
    *(short8*)(thetaPl + off) = lv;
  }
}

// ---------------- K2: bilinear + phi conv + patch L2-norm -> Bh/Bl [b][n=256][k=288] ----------------
__global__ __launch_bounds__(256) void k_phiphin(const float* __restrict__ x,
                      const float* __restrict__ phi_w, const float* __restrict__ phi_b,
                      const float* __restrict__ phi_alpha,
                      short* __restrict__ Bh, short* __restrict__ Bl) {
  int b = blockIdx.x;
  int t = threadIdx.x;             // = ij
  int i = t >> 4, j = t & 15;
  __shared__ float pw[64 * 32];
  __shared__ float pb[32], pa[32];
  __shared__ float ph_s[256 * 33];
  __shared__ float ss[256];
  for (int idx = t; idx < 512; idx += 256) ((float4*)pw)[idx] = ((const float4*)phi_w)[idx];
  if (t < 32) { pb[t] = phi_b[t]; pa[t] = phi_alpha[t]; }
  __syncthreads();
  const float* xb = x + (size_t)b * 4096 * 64;
  int r0 = 4 * i + 1, c0 = 4 * j + 1;
  const float* p00 = xb + ((size_t)r0 * 64 + c0) * 64;
  float acc[32];
  #pragma unroll
  for (int c = 0; c < 32; ++c) acc[c] = pb[c];
  for (int kq = 0; kq < 16; ++kq) {
    float4 a = ((const float4*)p00)[kq];
    float4 bq = ((const float4*)(p00 + 64))[kq];
    float4 cq = ((const float4*)(p00 + 4096))[kq];
    float4 dq = ((const float4*)(p00 + 4160))[kq];
    float xv[4] = {0.25f * (a.x + bq.x + cq.x + dq.x), 0.25f * (a.y + bq.y + cq.y + dq.y),
                   0.25f * (a.z + bq.z + cq.z + dq.z), 0.25f * (a.w + bq.w + cq.w + dq.w)};
    #pragma unroll
    for (int e = 0; e < 4; ++e) {
      const float* pwr = pw + (kq * 4 + e) * 32;
      #pragma unroll
      for (int c = 0; c < 32; ++c) acc[c] += xv[e] * pwr[c];
    }
  }
  float sum2 = 0.f;
  #pragma unroll
  for (int c = 0; c < 32; ++c) {
    float v = acc[c];
    v = v >= 0.f ? v : pa[c] * v;
    ph_s[t * 33 + c] = v;
    sum2 += v * v;
  }
  ss[t] = sum2;
  __syncthreads();
  float nn = 0.f;
  #pragma unroll
  for (int di = 0; di < 3; ++di)
    #pragma unroll
    for (int dj = 0; dj < 3; ++dj) {
      int pi = i + di - 1, pj = j + dj - 1;
      if (pi >= 0 && pi < 16 && pj >= 0 && pj < 16) nn += ss[pi * 16 + pj];
    }
  float scale = 1.f / fmaxf(sqrtf(nn), 1e-6f);
  size_t base = ((size_t)b * 256 + t) * 288;
  #pragma unroll
  for (int s = 0; s < 9; ++s) {
    int pi = i + s / 3 - 1, pj = j + s % 3 - 1;
    bool ok = pi >= 0 && pi < 16 && pj >= 0 && pj < 16;
    #pragma unroll
    for (int c = 0; c < 32; ++c) {
      float v = ok ? ph_s[(pi * 16 + pj) * 33 + c] * scale : 0.f;
      short hi = f2bf(v);
      Bh[base + s * 32 + c] = hi;
      Bl[base + s * 32 + c] = f2bf(v - bf2f(hi));
    }
  }
}

// ---------------- K3: scores via MFMA (bf16x3) + fused softmax -> attnp bf16 padded ----------------
__global__ __launch_bounds__(512) void k_sattn(const short* __restrict__ thetaPh,
                                               const short* __restrict__ thetaPl,
                                               const short* __restrict__ Bh,
                                               const short* __restrict__ Bl,
                                               short* __restrict__ attnp) {
  int mt = blockIdx.x;             // 0..31
  int b  = blockIdx.y;             // 0..7
  int tid = threadIdx.x;
  int w = tid >> 6, lane = tid & 63;
  int wm = w >> 2, wn = w & 3;
  int quad = lane >> 4, l16 = lane & 15;

  __shared__ __align__(16) short smem[32768];        // 64 KB
  short* As = smem;                                  // 512 slots x 8 shorts
  short* Bs = smem + 4096;                           // 1024 slots x 8 shorts
  float* wred = (float*)(smem + 12288);              // 128*4 floats

  f32x4 acc[4][4];
  #pragma unroll
  for (int i = 0; i < 4; ++i)
    #pragma unroll
    for (int j = 0; j < 4; ++j) acc[i][j] = (f32x4)0.f;

  // A staging decode: slot = w*64 + lane
  int slA = w * 64 + lane;
  int rA = (slA >> 8) * 64 + ((slA >> 6) & 3) * 16 + (slA & 15);
  int qA8 = ((slA >> 4) & 3) * 8;
  int am = mt * 128 + rA;
  int aQy = am >> 6, aQx = am & 63;
  // B staging decode: slot = w*128 + p*64 + lane
  int rB[2], qB8[2];
  #pragma unroll
  for (int p = 0; p < 2; ++p) {
    int sl = w * 128 + p * 64 + lane;
    rB[p] = (sl >> 8) * 64 + ((sl >> 6) & 3) * 16 + (sl & 15);
    qB8[p] = ((sl >> 4) & 3) * 8;
  }

  for (int kb = 0; kb < 27; ++kb) {
    int t = kb / 9, s = kb % 9;
    int di = s / 3, dj = s % 3;
    const short* Aarr = (t < 2) ? thetaPh : thetaPl;
    const short* Barr = (t == 1) ? Bl : Bh;
    __syncthreads();
    gload_lds16(Aarr + ((size_t)(b * 66 + aQy + di) * 66 + (aQx + dj)) * 32 + qA8,
                As + slA * 8);
    #pragma unroll
    for (int p = 0; p < 2; ++p)
      gload_lds16(Barr + ((size_t)(b * 256 + rB[p])) * 288 + s * 32 + qB8[p],
                  Bs + (w * 128 + p * 64 + lane) * 8);
    __syncthreads();
    short8 af[4], bfr[4];
    #pragma unroll
    for (int i = 0; i < 4; ++i)
      af[i] = *(const short8*)(As + ((((wm * 4 + i) * 4 + quad) * 16) + l16) * 8);
    #pragma unroll
    for (int j = 0; j < 4; ++j)
      bfr[j] = *(const short8*)(Bs + ((((wn * 4 + j) * 4 + quad) * 16) + l16) * 8);
    #pragma unroll
    for (int i = 0; i < 4; ++i)
      #pragma unroll
      for (int j = 0; j < 4; ++j)
        acc[i][j] = __builtin_amdgcn_mfma_f32_16x16x32_bf16(af[i], bfr[j], acc[i][j], 0, 0, 0);
  }

  // ---- fused softmax over n=256 ----
  float rmax[4][4];
  #pragma unroll
  for (int i = 0; i < 4; ++i)
    #pragma unroll
    for (int reg = 0; reg < 4; ++reg) {
      float m = -1e30f;
      #pragma unroll
      for (int j = 0; j < 4; ++j) m = fmaxf(m, acc[i][j][reg]);
      #pragma unroll
      for (int off = 1; off < 16; off <<= 1) m = fmaxf(m, __shfl_xor(m, off));
      rmax[i][reg] = m;
    }
  if (l16 == 0) {
    #pragma unroll
    for (int i = 0; i < 4; ++i)
      #pragma unroll
      for (int reg = 0; reg < 4; ++reg)
        wred[(wm * 64 + i * 16 + quad * 4 + reg) * 4 + wn] = rmax[i][reg];
  }
  __syncthreads();
  #pragma unroll
  for (int i = 0; i < 4; ++i)
    #pragma unroll
    for (int reg = 0; reg < 4; ++reg) {
      int r = wm * 64 + i * 16 + quad * 4 + reg;
      rmax[i][reg] = fmaxf(fmaxf(wred[r * 4 + 0], wred[r * 4 + 1]),
                           fmaxf(wred[r * 4 + 2], wred[r * 4 + 3]));
    }
  __syncthreads();
  float rsum[4][4];
  #pragma unroll
  for (int i = 0; i < 4; ++i)
    #pragma unroll
    for (int reg = 0; reg < 4; ++reg) {
      float s = 0.f;
      #pragma unroll
      for (int j = 0; j < 4; ++j) {
        float e = expf((acc[i][j][reg] - rmax[i][reg]) * 10.f);
        acc[i][j][reg] = e;
        s += e;
      }
      #pragma unroll
      for (int off = 1; off < 16; off <<= 1) s += __shfl_xor(s, off);
      rsum[i][reg] = s;
    }
  if (l16 == 0) {
    #pragma unroll
    for (int i = 0; i < 4; ++i)
      #pragma unroll
      for (int reg = 0; reg < 4; ++reg)
        wred[(wm * 64 + i * 16 + quad * 4 + reg) * 4 + wn] = rsum[i][reg];
  }
  __syncthreads();
  #pragma unroll
  for (int i = 0; i < 4; ++i)
    #pragma unroll
    for (int reg = 0; reg < 4; ++reg) {
      int r = wm * 64 + i * 16 + quad * 4 + reg;
      float tot = wred[r * 4 + 0] + wred[r * 4 + 1] + wred[r * 4 + 2] + wred[r * 4 + 3];
      rsum[i][reg] = 1.f / tot;
    }
  __syncthreads();
  #pragma unroll
  for (int i = 0; i < 4; ++i)
    #pragma unroll
    for (int reg = 0; reg < 4; ++reg) {
      int r = wm * 64 + i * 16 + quad * 4 + reg;
      #pragma unroll
      for (int j = 0; j < 4; ++j)
        smem[r * 256 + wn * 64 + j * 16 + l16] = f2bf(acc[i][j][reg] * rsum[i][reg]);
    }
  __syncthreads();
  {
    int r2 = tid >> 2, c2 = (tid & 3) * 64;
    int m2 = mt * 128 + r2;
    int Qy = m2 >> 6, Qx = m2 & 63;
    short8* dst = (short8*)(attnp + ((size_t)(b * 66 + Qy + 1) * 66 + (Qx + 1)) * 256 + c2);
    #pragma unroll
    for (int q = 0; q < 8; ++q) dst[q] = *(const short8*)(smem + r2 * 256 + c2 + q * 8);
  }
}

// ---------------- K4a: gather g -> Bbf[b][n=(ry,rx,c)=1024][k=(dy,dx,i,j)=2304] bf16 ----------------
// Block = (r, bl). LDS transpose tile: coalesced reads of g AND coalesced writes of Bbf.
__global__ __launch_bounds__(256) void k_bgather(const float* __restrict__ g,
                                                 short* __restrict__ Bbf) {
  int r = blockIdx.x;              // 0..15 = (ry,rx)
  int bl = blockIdx.y;
  int ry = r >> 2, rx = r & 3;
  int t = threadIdx.x;
  int wv = t >> 6, l = t & 63;
  int jj = t >> 4, c4 = (t & 15) * 4;
  __shared__ short tile[256 * 66];   // [ij][c], stride 66 (odd dword count)
  const float* gb = g + (size_t)bl * 4096 * 64;
  for (int s = 0; s < 9; ++s) {
    int dy = s / 3, dx = s % 3;
    {
      int col = 4 * jj + rx + 4 * dx - 4;
      #pragma unroll
      for (int i2 = 0; i2 < 16; ++i2) {
        int row = 4 * i2 + ry + 4 * dy - 4;
        float4 v = make_float4(0.f, 0.f, 0.f, 0.f);
        if (row >= 0 && row < 64 && col >= 0 && col < 64)
          v = *(const float4*)(gb + (((size_t)row << 6) + col) * 64 + c4);
        int ij = i2 * 16 + jj;
        tile[ij * 66 + c4 + 0] = f2bf(v.x);
        tile[ij * 66 + c4 + 1] = f2bf(v.y);
        tile[ij * 66 + c4 + 2] = f2bf(v.z);
        tile[ij * 66 + c4 + 3] = f2bf(v.w);
      }
    }
    __syncthreads();
    #pragma unroll
    for (int cc = 0; cc < 16; ++cc) {
      int c = cc * 4 + wv;
      int n = r * 64 + c;
      unsigned* dstrow = (unsigned*)(Bbf + ((size_t)bl * 1024 + n) * 2304 + s * 256);
      #pragma unroll
      for (int half = 0; half < 2; ++half) {
        int ij0 = half * 128 + 2 * l;
        unsigned v = (unsigned)(unsigned short)tile[ij0 * 66 + c]
                   | ((unsigned)(unsigned short)tile[(ij0 + 1) * 66 + c] << 16);
        dstrow[half * 64 + l] = v;
      }
    }
    __syncthreads();
  }
}

// ---------------- K4b: deconv as MFMA GEMM (conflict-free fragment-order LDS) ----------------
__global__ __launch_bounds__(256) void k_gemm(const short* __restrict__ attnp,
                                              const short* __restrict__ Bbf,
                                              float* __restrict__ out,
                                              int b0) {
  int mt = blockIdx.x;             // 0..31
  int nt = blockIdx.y;             // 0..7
  int bl = blockIdx.z;
  int b = b0 + bl;
  int tid = threadIdx.x;
  int wave = tid >> 6, lane = tid & 63;
  int wm = wave >> 1, wn = wave & 1;
  int quad = lane >> 4, l16 = lane & 15;

  __shared__ __align__(16) short As[4096];
  __shared__ __align__(16) short Bs[4096];

  f32x4 acc[4][4];
  #pragma unroll
  for (int i = 0; i < 4; ++i)
    #pragma unroll
    for (int j = 0; j < 4; ++j) acc[i][j] = (f32x4)0.f;

  const short* Ab = attnp + (size_t)b * 66 * 66 * 256;
  const short* Bb = Bbf + (size_t)bl * 1024 * 2304 + (size_t)(nt * 128) * 2304;

  // staging decode: slot = wave*128 + t*64 + lane, t in {0,1}
  int aQy[2], aQx[2], qA8[2], rB[2], qB8[2];
  #pragma unroll
  for (int t = 0; t < 2; ++t) {
    int sl = wave * 128 + t * 64 + lane;
    int rr = (sl >> 8) * 64 + ((sl >> 6) & 3) * 16 + (sl & 15);
    int q8 = ((sl >> 4) & 3) * 8;
    int m = mt * 128 + rr;
    aQy[t] = m >> 6; aQx[t] = m & 63; qA8[t] = q8;
    rB[t] = rr; qB8[t] = q8;
  }

  for (int kb = 0; kb < 72; ++kb) {
    int s = kb >> 3;
    int dy = s / 3, dx = s % 3;
    int n0 = (kb & 7) * 32;
    __syncthreads();
    #pragma unroll
    for (int t = 0; t < 2; ++t) {
      int hh = aQy[t] + 2 - dy;
      int wwp = aQx[t] + 2 - dx;
      gload_lds16(Ab + ((size_t)(hh * 66 + wwp) << 8) + n0 + qA8[t],
                  As + (wave * 128 + t * 64 + lane) * 8);
      gload_lds16(Bb + (size_t)rB[t] * 2304 + kb * 32 + qB8[t],
                  Bs + (wave * 128 + t * 64 + lane) * 8);
    }
    __syncthreads();
    short8 af[4], bfr[4];
    #pragma unroll
    for (int i = 0; i < 4; ++i)
      af[i] = *(const short8*)(As + ((((wm * 4 + i) * 4 + quad) * 16) + l16) * 8);
    #pragma unroll
    for (int j = 0; j < 4; ++j)
      bfr[j] = *(const short8*)(Bs + ((((wn * 4 + j) * 4 + quad) * 16) + l16) * 8);
    #pragma unroll
    for (int i = 0; i < 4; ++i)
      #pragma unroll
      for (int j = 0; j < 4; ++j)
        acc[i][j] = __builtin_amdgcn_mfma_f32_16x16x32_bf16(af[i], bfr[j], acc[i][j], 0, 0, 0);
  }

  const float inv6 = 1.f / 6.f;
  #pragma unroll
  for (int i = 0; i < 4; ++i) {
    int mbase = mt * 128 + wm * 64 + i * 16 + quad * 4;
    #pragma unroll
    for (int j = 0; j < 4; ++j) {
      int n = nt * 128 + wn * 64 + j * 16 + l16;
      int r = n >> 6; int c = n & 63;
      int ry = r >> 2, rx = r & 3;
      #pragma unroll
      for (int reg = 0; reg < 4; ++reg) {
        int m = mbase + reg;
        int Qy = m >> 6, Qx = m & 63;
        out[(((size_t)b * 256 + 4 * Qy + ry) * 256 + (4 * Qx + rx)) * 64 + c]
            = acc[i][j][reg] * inv6;
      }
    }
  }
}

extern "C" void kernel_launch(void* const* d_in, const int* in_sizes, int n_in,
                              void* d_out, int out_size, void* d_ws, size_t ws_size,
                              hipStream_t stream) {
  const float* x           = (const float*)d_in[0];
  const float* theta_w     = (const float*)d_in[1];
  const float* theta_b     = (const float*)d_in[2];
  const float* theta_alpha = (const float*)d_in[3];
  const float* phi_w       = (const float*)d_in[4];
  const float* phi_b       = (const float*)d_in[5];
  const float* phi_alpha   = (const float*)d_in[6];
  const float* g_w         = (const float*)d_in[7];
  const float* g_b         = (const float*)d_in[8];
  const float* g_alpha     = (const float*)d_in[9];
  float* out = (float*)d_out;

  char* w = (char*)d_ws;
  size_t off = 0;
  auto alloc = [&](size_t bytes) { void* p = w + off; off += (bytes + 255) & ~255ull; return p; };
  float* g       = (float*)alloc(8ull * 4096 * 64 * 4);       // 8 MB
  size_t thp_bytes = 8ull * 66 * 66 * 32 * 2;                 // 2.23 MB
  short* thetaPh = (short*)alloc(thp_bytes);
  short* thetaPl = (short*)alloc(thp_bytes);
  short* Bh      = (short*)alloc(8ull * 256 * 288 * 2);       // 1.18 MB
  short* Bl      = (short*)alloc(8ull * 256 * 288 * 2);
  size_t attnp_bytes = 8ull * 66 * 66 * 256 * 2;              // 17.8 MB
  short* attnp   = (short*)alloc(attnp_bytes);
  size_t bbf_full = 8ull * 1024 * 2304 * 2;                   // 37.7 MB
  bool full = (off + bbf_full) <= ws_size;
  short* Bbf = (short*)alloc(full ? bbf_full : bbf_full / 8);

  hipMemsetAsync(thetaPh, 0, thp_bytes, stream);
  hipMemsetAsync(thetaPl, 0, thp_bytes, stream);
  hipMemsetAsync(attnp, 0, attnp_bytes, stream);

  hipLaunchKernelGGL(k_theta_g, dim3(BB * 32), dim3(256), 0, stream,
                     x, theta_w, theta_b, theta_alpha, g_w, g_b, g_alpha,
                     thetaPh, thetaPl, g);
  hipLaunchKernelGGL(k_phiphin, dim3(BB), dim3(256), 0, stream,
                     x, phi_w, phi_b, phi_alpha, Bh, Bl);
  hipLaunchKernelGGL(k_sattn, dim3(32, BB), dim3(512), 0, stream,
                     thetaPh, thetaPl, Bh, Bl, attnp);
  if (full) {
    hipLaunchKernelGGL(k_bgather, dim3(16, BB), dim3(256), 0, stream, g, Bbf);
    hipLaunchKernelGGL(k_gemm, dim3(32, 8, BB), dim3(256), 0, stream, attnp, Bbf, out, 0);
  } else {
    for (int b = 0; b < BB; ++b) {
      hipLaunchKernelGGL(k_bgather, dim3(16, 1), dim3(256), 0, stream,
                         g + (size_t)b * 4096 * 64, Bbf);
      hipLaunchKernelGGL(k_gemm, dim3(32, 8, 1), dim3(256), 0, stream, attnp, Bbf, out, b);
    }
  }
}

// Round 5
// 502.024 us; speedup vs baseline: 1.2022x; 1.2022x over previous
//
#include <hip/hip_runtime.h>
#include <math.h>

// Problem constants: B=8, H=W=64, C=64, CI=32, SCALE=4, PATCH=3, N=256
#define BB 8

typedef __attribute__((ext_vector_type(8))) short short8;   // 8 x bf16 bits
typedef __attribute__((ext_vector_type(4))) float f32x4;

__device__ inline short f2bf(float x) {          // fp32 -> bf16 (RNE)
  unsigned u = __builtin_bit_cast(unsigned, x);
  u += 0x7fffu + ((u >> 16) & 1u);
  return (short)(u >> 16);
}
__device__ inline float bf2f(short h) {
  unsigned u = ((unsigned)(unsigned short)h) << 16;
  return __builtin_bit_cast(float, u);
}

__device__ inline void gload_lds16(const void* g, void* l) {
  __builtin_amdgcn_global_load_lds(
      (const __attribute__((address_space(1))) void*)g,
      (__attribute__((address_space(3))) void*)l, 16, 0, 0);
}

// Map ring-pixel index p (0..259) of a 66x66 frame to (row, col).
__device__ inline void ring_px(int p, int& r, int& cc) {
  if (p < 66) { r = 0; cc = p; }
  else if (p < 132) { r = 65; cc = p - 66; }
  else { int q = p - 132; r = 1 + (q >> 1); cc = (q & 1) ? 65 : 0; }
}

// ---------------- K1: theta & g conv1x1 + prelu (LDS-tiled) ----------------
// grid: 8 b x 32 pixel-groups (128 px each), 256 threads.
// Also zeroes the thetaP ring (block pg covers ring chunks c = pg + 32*t).
__global__ __launch_bounds__(256) void k_theta_g(const float* __restrict__ x,
                          const float* __restrict__ theta_w, const float* __restrict__ theta_b,
                          const float* __restrict__ theta_alpha,
                          const float* __restrict__ g_w, const float* __restrict__ g_b,
                          const float* __restrict__ g_alpha,
                          short* __restrict__ thetaPh, short* __restrict__ thetaPl,
                          float* __restrict__ g) {
  int bid = blockIdx.x;
  int b = bid >> 5, pg = bid & 31;
  int px0 = pg * 128;
  int tid = threadIdx.x;
  // ---- zero thetaP ring: 260 px * 32 ch = 1040 chunks of 8 shorts per array ----
  if (tid <= 32) {
    int c = pg + 32 * tid;
    if (c < 1040) {
      int p = c >> 2, off = (c & 3) * 8;
      int r, cc; ring_px(p, r, cc);
      size_t ad = ((size_t)(b * 66 + r) * 66 + cc) * 32 + off;
      short8 z = (short8)0;
      *(short8*)(thetaPh + ad) = z;
      *(short8*)(thetaPl + ad) = z;
    }
  }
  __shared__ float gw[64 * 64];     // [k][c]
  __shared__ float tw[64 * 32];     // [k][c]
  __shared__ float xs[64 * 128];    // [k][p]  (transposed)
  __shared__ float gb_s[64], ga_s[64], tb_s[32], ta_s[32];
  for (int idx = tid; idx < 1024; idx += 256) ((float4*)gw)[idx] = ((const float4*)g_w)[idx];
  for (int idx = tid; idx < 512; idx += 256)  ((float4*)tw)[idx] = ((const float4*)theta_w)[idx];
  if (tid < 64) { gb_s[tid] = g_b[tid]; ga_s[tid] = g_alpha[tid]; }
  else if (tid < 96) { tb_s[tid - 64] = theta_b[tid - 64]; ta_s[tid - 64] = theta_alpha[tid - 64]; }
  {
    int p = tid >> 1, half = tid & 1;
    const float* xp = x + ((size_t)b * 4096 + px0 + p) * 64 + half * 32;
    #pragma unroll
    for (int i = 0; i < 8; ++i) {
      float4 v = ((const float4*)xp)[i];
      int k = half * 32 + i * 4;
      xs[(k + 0) * 128 + p] = v.x; xs[(k + 1) * 128 + p] = v.y;
      xs[(k + 2) * 128 + p] = v.z; xs[(k + 3) * 128 + p] = v.w;
    }
  }
  __syncthreads();
  int pp = tid >> 2, q = tid & 3;
  float accg[2][16], acct[2][8];
  #pragma unroll
  for (int c = 0; c < 16; ++c) { float bv = gb_s[q * 16 + c]; accg[0][c] = bv; accg[1][c] = bv; }
  #pragma unroll
  for (int c = 0; c < 8; ++c)  { float bv = tb_s[q * 8 + c];  acct[0][c] = bv; acct[1][c] = bv; }
  for (int k = 0; k < 64; ++k) {
    float x0 = xs[k * 128 + 2 * pp], x1 = xs[k * 128 + 2 * pp + 1];
    const float* gwr = gw + k * 64 + q * 16;
    const float* twr = tw + k * 32 + q * 8;
    #pragma unroll
    for (int c = 0; c < 16; ++c) { float wv = gwr[c]; accg[0][c] += x0 * wv; accg[1][c] += x1 * wv; }
    #pragma unroll
    for (int c = 0; c < 8; ++c)  { float wv = twr[c]; acct[0][c] += x0 * wv; acct[1][c] += x1 * wv; }
  }
  #pragma unroll
  for (int e = 0; e < 2; ++e) {
    int px = px0 + 2 * pp + e;
    float* gp = g + ((size_t)b * 4096 + px) * 64 + q * 16;
    #pragma unroll
    for (int c4 = 0; c4 < 4; ++c4) {
      float4 v;
      v.x = accg[e][c4*4+0]; v.y = accg[e][c4*4+1]; v.z = accg[e][c4*4+2]; v.w = accg[e][c4*4+3];
      float a0 = ga_s[q*16+c4*4+0], a1 = ga_s[q*16+c4*4+1], a2 = ga_s[q*16+c4*4+2], a3 = ga_s[q*16+c4*4+3];
      v.x = v.x >= 0.f ? v.x : a0 * v.x; v.y = v.y >= 0.f ? v.y : a1 * v.y;
      v.z = v.z >= 0.f ? v.z : a2 * v.z; v.w = v.w >= 0.f ? v.w : a3 * v.w;
      ((float4*)gp)[c4] = v;
    }
    int h = px >> 6, w = px & 63;
    size_t off = ((size_t)(b * 66 + h + 1) * 66 + (w + 1)) * 32 + q * 8;
    short8 hv, lv;
    #pragma unroll
    for (int c = 0; c < 8; ++c) {
      float t = acct[e][c];
      float a = ta_s[q * 8 + c];
      float v = t >= 0.f ? t : a * t;
      short hi = f2bf(v);
      hv[c] = hi;
      lv[c] = f2bf(v - bf2f(hi));
    }
    *(short8*)(thetaPh + off) = hv;
    *(short8*)(thetaPl + off) = lv;
  }
}

// ---------------- K2: bilinear + phi conv + patch L2-norm -> Bh/Bl [b][n=256][k=288] ----------------
__global__ __launch_bounds__(256) void k_phiphin(const float* __restrict__ x,
                      const float* __restrict__ phi_w, const float* __restrict__ phi_b,
                      const float* __restrict__ phi_alpha,
                      short* __restrict__ Bh, short* __restrict__ Bl) {
  int b = blockIdx.x;
  int t = threadIdx.x;             // = ij
  int i = t >> 4, j = t & 15;
  __shared__ float pw[64 * 32];
  __shared__ float pb[32], pa[32];
  __shared__ float ph_s[256 * 33];
  __shared__ float ss[256];
  for (int idx = t; idx < 512; idx += 256) ((float4*)pw)[idx] = ((const float4*)phi_w)[idx];
  if (t < 32) { pb[t] = phi_b[t]; pa[t] = phi_alpha[t]; }
  __syncthreads();
  const float* xb = x + (size_t)b * 4096 * 64;
  int r0 = 4 * i + 1, c0 = 4 * j + 1;
  const float* p00 = xb + ((size_t)r0 * 64 + c0) * 64;
  float acc[32];
  #pragma unroll
  for (int c = 0; c < 32; ++c) acc[c] = pb[c];
  for (int kq = 0; kq < 16; ++kq) {
    float4 a = ((const float4*)p00)[kq];
    float4 bq = ((const float4*)(p00 + 64))[kq];
    float4 cq = ((const float4*)(p00 + 4096))[kq];
    float4 dq = ((const float4*)(p00 + 4160))[kq];
    float xv[4] = {0.25f * (a.x + bq.x + cq.x + dq.x), 0.25f * (a.y + bq.y + cq.y + dq.y),
                   0.25f * (a.z + bq.z + cq.z + dq.z), 0.25f * (a.w + bq.w + cq.w + dq.w)};
    #pragma unroll
    for (int e = 0; e < 4; ++e) {
      const float* pwr = pw + (kq * 4 + e) * 32;
      #pragma unroll
      for (int c = 0; c < 32; ++c) acc[c] += xv[e] * pwr[c];
    }
  }
  float sum2 = 0.f;
  #pragma unroll
  for (int c = 0; c < 32; ++c) {
    float v = acc[c];
    v = v >= 0.f ? v : pa[c] * v;
    ph_s[t * 33 + c] = v;
    sum2 += v * v;
  }
  ss[t] = sum2;
  __syncthreads();
  float nn = 0.f;
  #pragma unroll
  for (int di = 0; di < 3; ++di)
    #pragma unroll
    for (int dj = 0; dj < 3; ++dj) {
      int pi = i + di - 1, pj = j + dj - 1;
      if (pi >= 0 && pi < 16 && pj >= 0 && pj < 16) nn += ss[pi * 16 + pj];
    }
  float scale = 1.f / fmaxf(sqrtf(nn), 1e-6f);
  size_t base = ((size_t)b * 256 + t) * 288;
  #pragma unroll
  for (int s = 0; s < 9; ++s) {
    int pi = i + s / 3 - 1, pj = j + s % 3 - 1;
    bool ok = pi >= 0 && pi < 16 && pj >= 0 && pj < 16;
    #pragma unroll
    for (int c = 0; c < 32; ++c) {
      float v = ok ? ph_s[(pi * 16 + pj) * 33 + c] * scale : 0.f;
      short hi = f2bf(v);
      Bh[base + s * 32 + c] = hi;
      Bl[base + s * 32 + c] = f2bf(v - bf2f(hi));
    }
  }
}

// ---------------- K3: scores via MFMA (bf16x3) + fused softmax -> attnp bf16 padded ----------------
// Round-3 staging layout (proven). Also zeroes 1/32 of batch b's attnp ring.
__global__ __launch_bounds__(512) void k_sattn(const short* __restrict__ thetaPh,
                                               const short* __restrict__ thetaPl,
                                               const short* __restrict__ Bh,
                                               const short* __restrict__ Bl,
                                               short* __restrict__ attnp) {
  int mt = blockIdx.x;             // 0..31
  int b  = blockIdx.y;             // 0..7
  int tid = threadIdx.x;
  // ---- zero attnp ring: 260 px * 256 ch = 8320 chunks of 8 shorts per batch ----
  {
    int c = mt + 32 * tid;         // tid < 260 covers c < 8320
    if (c < 8320) {
      int p = c >> 5, off = (c & 31) * 8;
      int r, cc; ring_px(p, r, cc);
      *(short8*)(attnp + ((size_t)(b * 66 + r) * 66 + cc) * 256 + off) = (short8)0;
    }
  }
  int w = tid >> 6, lane = tid & 63;
  int wm = w >> 2, wn = w & 3;
  int quad = lane >> 4, l16 = lane & 15;

  __shared__ __align__(16) short smem[32768];        // 64 KB
  short* As = smem;                                  // 128*32
  short* Bs = smem + 4096;                           // 256*32
  float* wred = (float*)(smem + 12288);              // 128*4 floats

  f32x4 acc[4][4];
  #pragma unroll
  for (int i = 0; i < 4; ++i)
    #pragma unroll
    for (int j = 0; j < 4; ++j) acc[i][j] = (f32x4)0.f;

  int ar = w * 16 + (lane >> 2);                     // As row 0..127
  int am = mt * 128 + ar;
  int aQy = am >> 6, aQx = am & 63;
  int achunk = (lane & 3) * 8;

  for (int kb = 0; kb < 27; ++kb) {
    int t = kb / 9, s = kb % 9;
    int di = s / 3, dj = s % 3;
    const short* Aarr = (t < 2) ? thetaPh : thetaPl;
    const short* Barr = (t == 1) ? Bl : Bh;
    __syncthreads();
    gload_lds16(Aarr + ((size_t)(b * 66 + aQy + di) * 66 + (aQx + dj)) * 32 + achunk,
                As + w * 512 + lane * 8);
    #pragma unroll
    for (int p = 0; p < 2; ++p) {
      int nl = w * 32 + p * 16 + (lane >> 2);
      gload_lds16(Barr + ((size_t)(b * 256 + nl)) * 288 + s * 32 + achunk,
                  Bs + w * 1024 + p * 512 + lane * 8);
    }
    __syncthreads();
    short8 af[4], bfr[4];
    #pragma unroll
    for (int i = 0; i < 4; ++i)
      af[i] = *(const short8*)(As + (wm * 64 + i * 16 + l16) * 32 + quad * 8);
    #pragma unroll
    for (int j = 0; j < 4; ++j)
      bfr[j] = *(const short8*)(Bs + (wn * 64 + j * 16 + l16) * 32 + quad * 8);
    #pragma unroll
    for (int i = 0; i < 4; ++i)
      #pragma unroll
      for (int j = 0; j < 4; ++j)
        acc[i][j] = __builtin_amdgcn_mfma_f32_16x16x32_bf16(af[i], bfr[j], acc[i][j], 0, 0, 0);
  }

  // ---- fused softmax over n=256 ----
  float rmax[4][4];
  #pragma unroll
  for (int i = 0; i < 4; ++i)
    #pragma unroll
    for (int reg = 0; reg < 4; ++reg) {
      float m = -1e30f;
      #pragma unroll
      for (int j = 0; j < 4; ++j) m = fmaxf(m, acc[i][j][reg]);
      #pragma unroll
      for (int off = 1; off < 16; off <<= 1) m = fmaxf(m, __shfl_xor(m, off));
      rmax[i][reg] = m;
    }
  if (l16 == 0) {
    #pragma unroll
    for (int i = 0; i < 4; ++i)
      #pragma unroll
      for (int reg = 0; reg < 4; ++reg)
        wred[(wm * 64 + i * 16 + quad * 4 + reg) * 4 + wn] = rmax[i][reg];
  }
  __syncthreads();
  #pragma unroll
  for (int i = 0; i < 4; ++i)
    #pragma unroll
    for (int reg = 0; reg < 4; ++reg) {
      int r = wm * 64 + i * 16 + quad * 4 + reg;
      rmax[i][reg] = fmaxf(fmaxf(wred[r * 4 + 0], wred[r * 4 + 1]),
                           fmaxf(wred[r * 4 + 2], wred[r * 4 + 3]));
    }
  __syncthreads();
  float rsum[4][4];
  #pragma unroll
  for (int i = 0; i < 4; ++i)
    #pragma unroll
    for (int reg = 0; reg < 4; ++reg) {
      float s = 0.f;
      #pragma unroll
      for (int j = 0; j < 4; ++j) {
        float e = expf((acc[i][j][reg] - rmax[i][reg]) * 10.f);
        acc[i][j][reg] = e;
        s += e;
      }
      #pragma unroll
      for (int off = 1; off < 16; off <<= 1) s += __shfl_xor(s, off);
      rsum[i][reg] = s;
    }
  if (l16 == 0) {
    #pragma unroll
    for (int i = 0; i < 4; ++i)
      #pragma unroll
      for (int reg = 0; reg < 4; ++reg)
        wred[(wm * 64 + i * 16 + quad * 4 + reg) * 4 + wn] = rsum[i][reg];
  }
  __syncthreads();
  #pragma unroll
  for (int i = 0; i < 4; ++i)
    #pragma unroll
    for (int reg = 0; reg < 4; ++reg) {
      int r = wm * 64 + i * 16 + quad * 4 + reg;
      float tot = wred[r * 4 + 0] + wred[r * 4 + 1] + wred[r * 4 + 2] + wred[r * 4 + 3];
      rsum[i][reg] = 1.f / tot;
    }
  __syncthreads();
  #pragma unroll
  for (int i = 0; i < 4; ++i)
    #pragma unroll
    for (int reg = 0; reg < 4; ++reg) {
      int r = wm * 64 + i * 16 + quad * 4 + reg;
      #pragma unroll
      for (int j = 0; j < 4; ++j)
        smem[r * 256 + wn * 64 + j * 16 + l16] = f2bf(acc[i][j][reg] * rsum[i][reg]);
    }
  __syncthreads();
  {
    int r2 = tid >> 2, c2 = (tid & 3) * 64;
    int m2 = mt * 128 + r2;
    int Qy = m2 >> 6, Qx = m2 & 63;
    short8* dst = (short8*)(attnp + ((size_t)(b * 66 + Qy + 1) * 66 + (Qx + 1)) * 256 + c2);
    #pragma unroll
    for (int q = 0; q < 8; ++q) dst[q] = *(const short8*)(smem + r2 * 256 + c2 + q * 8);
  }
}

// ---------------- K4a: gather g -> Bbf[b][n=(ry,rx,c)=1024][k=(dy,dx,i,j)=2304] bf16 ----------------
__global__ __launch_bounds__(256) void k_bgather(const float* __restrict__ g,
                                                 short* __restrict__ Bbf) {
  int r = blockIdx.x;              // 0..15 = (ry,rx)
  int bl = blockIdx.y;
  int ry = r >> 2, rx = r & 3;
  int t = threadIdx.x;
  int wv = t >> 6, l = t & 63;
  int jj = t >> 4, c4 = (t & 15) * 4;
  __shared__ short tile[256 * 66];   // [ij][c], stride 66
  const float* gb = g + (size_t)bl * 4096 * 64;
  for (int s = 0; s < 9; ++s) {
    int dy = s / 3, dx = s % 3;
    {
      int col = 4 * jj + rx + 4 * dx - 4;
      #pragma unroll
      for (int i2 = 0; i2 < 16; ++i2) {
        int row = 4 * i2 + ry + 4 * dy - 4;
        float4 v = make_float4(0.f, 0.f, 0.f, 0.f);
        if (row >= 0 && row < 64 && col >= 0 && col < 64)
          v = *(const float4*)(gb + (((size_t)row << 6) + col) * 64 + c4);
        int ij = i2 * 16 + jj;
        tile[ij * 66 + c4 + 0] = f2bf(v.x);
        tile[ij * 66 + c4 + 1] = f2bf(v.y);
        tile[ij * 66 + c4 + 2] = f2bf(v.z);
        tile[ij * 66 + c4 + 3] = f2bf(v.w);
      }
    }
    __syncthreads();
    #pragma unroll
    for (int cc = 0; cc < 16; ++cc) {
      int c = cc * 4 + wv;
      int n = r * 64 + c;
      unsigned* dstrow = (unsigned*)(Bbf + ((size_t)bl * 1024 + n) * 2304 + s * 256);
      #pragma unroll
      for (int half = 0; half < 2; ++half) {
        int ij0 = half * 128 + 2 * l;
        unsigned v = (unsigned)(unsigned short)tile[ij0 * 66 + c]
                   | ((unsigned)(unsigned short)tile[(ij0 + 1) * 66 + c] << 16);
        dstrow[half * 64 + l] = v;
      }
    }
    __syncthreads();
  }
}

// ---------------- K4b: deconv as MFMA GEMM (round-3 proven layout) ----------------
__global__ __launch_bounds__(256) void k_gemm(const short* __restrict__ attnp,
                                              const short* __restrict__ Bbf,
                                              float* __restrict__ out,
                                              int b0) {
  int mt = blockIdx.x;             // 0..31
  int nt = blockIdx.y;             // 0..7
  int bl = blockIdx.z;
  int b = b0 + bl;
  int tid = threadIdx.x;
  int wave = tid >> 6, lane = tid & 63;
  int wm = wave >> 1, wn = wave & 1;
  int quad = lane >> 4, l16 = lane & 15;

  __shared__ __align__(16) short As[128 * 32];
  __shared__ __align__(16) short Bs[128 * 32];

  f32x4 acc[4][4];
  #pragma unroll
  for (int i = 0; i < 4; ++i)
    #pragma unroll
    for (int j = 0; j < 4; ++j) acc[i][j] = (f32x4)0.f;

  const short* Ab = attnp + (size_t)b * 66 * 66 * 256;
  const short* Bb = Bbf + (size_t)bl * 1024 * 2304 + (size_t)(nt * 128) * 2304;

  int larow = lane >> 2;
  int lakq  = lane & 3;
  short* Adst = As + wave * 1024 + lane * 8;
  short* Bdst = Bs + wave * 1024 + lane * 8;

  for (int kb = 0; kb < 72; ++kb) {
    int s = kb >> 3;
    int dy = s / 3, dx = s % 3;
    int n0 = (kb & 7) * 32;
    __syncthreads();
    #pragma unroll
    for (int t = 0; t < 2; ++t) {
      int rr = wave * 32 + t * 16 + larow;
      int m = mt * 128 + rr;
      int hh = (m >> 6) + 2 - dy;
      int wwp = (m & 63) + 2 - dx;
      gload_lds16(Ab + ((size_t)(hh * 66 + wwp) << 8) + n0 + lakq * 8,
                  Adst + t * 512);
      gload_lds16(Bb + (size_t)rr * 2304 + kb * 32 + lakq * 8,
                  Bdst + t * 512);
    }
    __syncthreads();
    short8 af[4], bfr[4];
    #pragma unroll
    for (int i = 0; i < 4; ++i)
      af[i] = *(const short8*)(As + (wm * 64 + i * 16 + l16) * 32 + quad * 8);
    #pragma unroll
    for (int j = 0; j < 4; ++j)
      bfr[j] = *(const short8*)(Bs + (wn * 64 + j * 16 + l16) * 32 + quad * 8);
    #pragma unroll
    for (int i = 0; i < 4; ++i)
      #pragma unroll
      for (int j = 0; j < 4; ++j)
        acc[i][j] = __builtin_amdgcn_mfma_f32_16x16x32_bf16(af[i], bfr[j], acc[i][j], 0, 0, 0);
  }

  const float inv6 = 1.f / 6.f;
  #pragma unroll
  for (int i = 0; i < 4; ++i) {
    int mbase = mt * 128 + wm * 64 + i * 16 + quad * 4;
    #pragma unroll
    for (int j = 0; j < 4; ++j) {
      int n = nt * 128 + wn * 64 + j * 16 + l16;
      int r = n >> 6; int c = n & 63;
      int ry = r >> 2, rx = r & 3;
      #pragma unroll
      for (int reg = 0; reg < 4; ++reg) {
        int m = mbase + reg;
        int Qy = m >> 6, Qx = m & 63;
        out[(((size_t)b * 256 + 4 * Qy + ry) * 256 + (4 * Qx + rx)) * 64 + c]
            = acc[i][j][reg] * inv6;
      }
    }
  }
}

extern "C" void kernel_launch(void* const* d_in, const int* in_sizes, int n_in,
                              void* d_out, int out_size, void* d_ws, size_t ws_size,
                              hipStream_t stream) {
  const float* x           = (const float*)d_in[0];
  const float* theta_w     = (const float*)d_in[1];
  const float* theta_b     = (const float*)d_in[2];
  const float* theta_alpha = (const float*)d_in[3];
  const float* phi_w       = (const float*)d_in[4];
  const float* phi_b       = (const float*)d_in[5];
  const float* phi_alpha   = (const float*)d_in[6];
  const float* g_w         = (const float*)d_in[7];
  const float* g_b         = (const float*)d_in[8];
  const float* g_alpha     = (const float*)d_in[9];
  float* out = (float*)d_out;

  char* w = (char*)d_ws;
  size_t off = 0;
  auto alloc = [&](size_t bytes) { void* p = w + off; off += (bytes + 255) & ~255ull; return p; };
  float* g       = (float*)alloc(8ull * 4096 * 64 * 4);       // 8 MB
  size_t thp_bytes = 8ull * 66 * 66 * 32 * 2;                 // 2.23 MB
  short* thetaPh = (short*)alloc(thp_bytes);
  short* thetaPl = (short*)alloc(thp_bytes);
  short* Bh      = (short*)alloc(8ull * 256 * 288 * 2);       // 1.18 MB
  short* Bl      = (short*)alloc(8ull * 256 * 288 * 2);
  size_t attnp_bytes = 8ull * 66 * 66 * 256 * 2;              // 17.8 MB
  short* attnp   = (short*)alloc(attnp_bytes);
  size_t bbf_full = 8ull * 1024 * 2304 * 2;                   // 37.7 MB
  bool full = (off + bbf_full) <= ws_size;
  short* Bbf = (short*)alloc(full ? bbf_full : bbf_full / 8);

  // No memsets: thetaP rings zeroed in k_theta_g, attnp ring zeroed in k_sattn.
  hipLaunchKernelGGL(k_theta_g, dim3(BB * 32), dim3(256), 0, stream,
                     x, theta_w, theta_b, theta_alpha, g_w, g_b, g_alpha,
                     thetaPh, thetaPl, g);
  hipLaunchKernelGGL(k_phiphin, dim3(BB), dim3(256), 0, stream,
                     x, phi_w, phi_b, phi_alpha, Bh, Bl);
  hipLaunchKernelGGL(k_sattn, dim3(32, BB), dim3(512), 0, stream,
                     thetaPh, thetaPl, Bh, Bl, attnp);
  if (full) {
    hipLaunchKernelGGL(k_bgather, dim3(16, BB), dim3(256), 0, stream, g, Bbf);
    hipLaunchKernelGGL(k_gemm, dim3(32, 8, BB), dim3(256), 0, stream, attnp, Bbf, out, 0);
  } else {
    for (int b = 0; b < BB; ++b) {
      hipLaunchKernelGGL(k_bgather, dim3(16, 1), dim3(256), 0, stream,
                         g + (size_t)b * 4096 * 64, Bbf);
      hipLaunchKernelGGL(k_gemm, dim3(32, 8, 1), dim3(256), 0, stream, attnp, Bbf, out, b);
    }
  }
}

// Round 6
// 399.251 us; speedup vs baseline: 1.5116x; 1.2574x over previous
//
#include <hip/hip_runtime.h>
#include <math.h>

// Problem constants: B=8, H=W=64, C=64, CI=32, SCALE=4, PATCH=3, N=256
#define BB 8

typedef __attribute__((ext_vector_type(8))) short short8;   // 8 x bf16 bits
typedef __attribute__((ext_vector_type(4))) float f32x4;

__device__ inline short f2bf(float x) {          // fp32 -> bf16 (RNE)
  unsigned u = __builtin_bit_cast(unsigned, x);
  u += 0x7fffu + ((u >> 16) & 1u);
  return (short)(u >> 16);
}
__device__ inline float bf2f(short h) {
  unsigned u = ((unsigned)(unsigned short)h) << 16;
  return __builtin_bit_cast(float, u);
}

__device__ inline void gload_lds16(const void* g, void* l) {
  __builtin_amdgcn_global_load_lds(
      (const __attribute__((address_space(1))) void*)g,
      (__attribute__((address_space(3))) void*)l, 16, 0, 0);
}

// Map ring-pixel index p (0..259) of a 66x66 frame to (row, col).
__device__ inline void ring_px(int p, int& r, int& cc) {
  if (p < 66) { r = 0; cc = p; }
  else if (p < 132) { r = 65; cc = p - 66; }
  else { int q = p - 132; r = 1 + (q >> 1); cc = (q & 1) ? 65 : 0; }
}

// ---------------- K1 (fused): blocks 0..255 = theta&g conv; 256..383 = phi+phin ----------------
__global__ __launch_bounds__(256) void k_pre(const float* __restrict__ x,
                          const float* __restrict__ theta_w, const float* __restrict__ theta_b,
                          const float* __restrict__ theta_alpha,
                          const float* __restrict__ phi_w, const float* __restrict__ phi_b,
                          const float* __restrict__ phi_alpha,
                          const float* __restrict__ g_w, const float* __restrict__ g_b,
                          const float* __restrict__ g_alpha,
                          short* __restrict__ thetaPh, short* __restrict__ thetaPl,
                          float* __restrict__ g,
                          short* __restrict__ Bh, short* __restrict__ Bl) {
  __shared__ __align__(16) float spool[14528];
  int tid = threadIdx.x;
  if (blockIdx.x < 256) {
    // ======== theta & g path (proven round-5 structure) ========
    int bid = blockIdx.x;
    int b = bid >> 5, pg = bid & 31;
    int px0 = pg * 128;
    // zero thetaP ring: 1040 short8-chunks per array per batch
    if (tid <= 32) {
      int c = pg + 32 * tid;
      if (c < 1040) {
        int p = c >> 2, off = (c & 3) * 8;
        int r, cc; ring_px(p, r, cc);
        size_t ad = ((size_t)(b * 66 + r) * 66 + cc) * 32 + off;
        short8 z = (short8)0;
        *(short8*)(thetaPh + ad) = z;
        *(short8*)(thetaPl + ad) = z;
      }
    }
    float* gw = spool;              // 64*64
    float* tw = spool + 4096;       // 64*32
    float* xs = spool + 6144;       // 64*128
    float* gb_s = spool + 14336; float* ga_s = spool + 14400;
    float* tb_s = spool + 14464; float* ta_s = spool + 14496;
    for (int idx = tid; idx < 1024; idx += 256) ((float4*)gw)[idx] = ((const float4*)g_w)[idx];
    for (int idx = tid; idx < 512; idx += 256)  ((float4*)tw)[idx] = ((const float4*)theta_w)[idx];
    if (tid < 64) { gb_s[tid] = g_b[tid]; ga_s[tid] = g_alpha[tid]; }
    else if (tid < 96) { tb_s[tid - 64] = theta_b[tid - 64]; ta_s[tid - 64] = theta_alpha[tid - 64]; }
    {
      int p = tid >> 1, half = tid & 1;
      const float* xp = x + ((size_t)b * 4096 + px0 + p) * 64 + half * 32;
      #pragma unroll
      for (int i = 0; i < 8; ++i) {
        float4 v = ((const float4*)xp)[i];
        int k = half * 32 + i * 4;
        xs[(k + 0) * 128 + p] = v.x; xs[(k + 1) * 128 + p] = v.y;
        xs[(k + 2) * 128 + p] = v.z; xs[(k + 3) * 128 + p] = v.w;
      }
    }
    __syncthreads();
    int pp = tid >> 2, q = tid & 3;
    float accg[2][16], acct[2][8];
    #pragma unroll
    for (int c = 0; c < 16; ++c) { float bv = gb_s[q * 16 + c]; accg[0][c] = bv; accg[1][c] = bv; }
    #pragma unroll
    for (int c = 0; c < 8; ++c)  { float bv = tb_s[q * 8 + c];  acct[0][c] = bv; acct[1][c] = bv; }
    for (int k = 0; k < 64; ++k) {
      float x0 = xs[k * 128 + 2 * pp], x1 = xs[k * 128 + 2 * pp + 1];
      const float* gwr = gw + k * 64 + q * 16;
      const float* twr = tw + k * 32 + q * 8;
      #pragma unroll
      for (int c = 0; c < 16; ++c) { float wv = gwr[c]; accg[0][c] += x0 * wv; accg[1][c] += x1 * wv; }
      #pragma unroll
      for (int c = 0; c < 8; ++c)  { float wv = twr[c]; acct[0][c] += x0 * wv; acct[1][c] += x1 * wv; }
    }
    #pragma unroll
    for (int e = 0; e < 2; ++e) {
      int px = px0 + 2 * pp + e;
      float* gp = g + ((size_t)b * 4096 + px) * 64 + q * 16;
      #pragma unroll
      for (int c4 = 0; c4 < 4; ++c4) {
        float4 v;
        v.x = accg[e][c4*4+0]; v.y = accg[e][c4*4+1]; v.z = accg[e][c4*4+2]; v.w = accg[e][c4*4+3];
        float a0 = ga_s[q*16+c4*4+0], a1 = ga_s[q*16+c4*4+1], a2 = ga_s[q*16+c4*4+2], a3 = ga_s[q*16+c4*4+3];
        v.x = v.x >= 0.f ? v.x : a0 * v.x; v.y = v.y >= 0.f ? v.y : a1 * v.y;
        v.z = v.z >= 0.f ? v.z : a2 * v.z; v.w = v.w >= 0.f ? v.w : a3 * v.w;
        ((float4*)gp)[c4] = v;
      }
      int h = px >> 6, w = px & 63;
      size_t off = ((size_t)(b * 66 + h + 1) * 66 + (w + 1)) * 32 + q * 8;
      short8 hv, lv;
      #pragma unroll
      for (int c = 0; c < 8; ++c) {
        float t = acct[e][c];
        float a = ta_s[q * 8 + c];
        float v = t >= 0.f ? t : a * t;
        short hi = f2bf(v);
        hv[c] = hi;
        lv[c] = f2bf(v - bf2f(hi));
      }
      *(short8*)(thetaPh + off) = hv;
      *(short8*)(thetaPl + off) = lv;
    }
  } else {
    // ======== phi + phin path: one block per (b, i-row), halo recomputed ========
    int bid = blockIdx.x - 256;
    int b = bid >> 4, irow = bid & 15;
    float* pw   = spool;            // 64*32
    float* pb   = spool + 2048;     // 32
    float* pa   = spool + 2080;     // 32
    float* ph_s = spool + 2112;     // 48*33
    float* ss2  = spool + 3696;     // 48
    float* ssp  = spool + 3744;     // 192
    for (int idx = tid; idx < 512; idx += 256) ((float4*)pw)[idx] = ((const float4*)phi_w)[idx];
    if (tid < 32) { pb[tid] = phi_b[tid]; pa[tid] = phi_alpha[tid]; }
    __syncthreads();
    // conv: threads t = lr*64 + j*4 + cg  (lr<3, j<16, cg<4 -> 8 channels each)
    if (tid < 192) {
      int lr = tid >> 6, j = (tid >> 2) & 15, cg = tid & 3;
      int i2 = irow + lr - 1;
      float acc8[8];
      float sum2 = 0.f;
      if (i2 >= 0 && i2 < 16) {
        #pragma unroll
        for (int c = 0; c < 8; ++c) acc8[c] = pb[cg * 8 + c];
        const float* xb = x + (size_t)b * 4096 * 64;
        const float* p00 = xb + ((size_t)(4 * i2 + 1) * 64 + (4 * j + 1)) * 64;
        for (int kq = 0; kq < 16; ++kq) {
          float4 a = ((const float4*)p00)[kq];
          float4 bq = ((const float4*)(p00 + 64))[kq];
          float4 cq = ((const float4*)(p00 + 4096))[kq];
          float4 dq = ((const float4*)(p00 + 4160))[kq];
          float xv[4] = {0.25f * (a.x + bq.x + cq.x + dq.x), 0.25f * (a.y + bq.y + cq.y + dq.y),
                         0.25f * (a.z + bq.z + cq.z + dq.z), 0.25f * (a.w + bq.w + cq.w + dq.w)};
          #pragma unroll
          for (int e = 0; e < 4; ++e) {
            const float* pwr = pw + (kq * 4 + e) * 32 + cg * 8;
            #pragma unroll
            for (int c = 0; c < 8; ++c) acc8[c] += xv[e] * pwr[c];
          }
        }
        #pragma unroll
        for (int c = 0; c < 8; ++c) {
          float v = acc8[c];
          v = v >= 0.f ? v : pa[cg * 8 + c] * v;
          ph_s[(lr * 16 + j) * 33 + cg * 8 + c] = v;
          sum2 += v * v;
        }
      } else {
        #pragma unroll
        for (int c = 0; c < 8; ++c) ph_s[(lr * 16 + j) * 33 + cg * 8 + c] = 0.f;
      }
      ssp[tid] = sum2;
    }
    __syncthreads();
    if (tid < 48) ss2[tid] = ssp[tid*4] + ssp[tid*4+1] + ssp[tid*4+2] + ssp[tid*4+3];
    __syncthreads();
    // write: thread = j*16 + u, u<9 = shift s
    int j = tid >> 4, u = tid & 15;
    if (u < 9) {
      float nn = 0.f;
      #pragma unroll
      for (int lr = 0; lr < 3; ++lr) {
        int i2 = irow + lr - 1;
        if (i2 < 0 || i2 > 15) continue;
        #pragma unroll
        for (int dj = 0; dj < 3; ++dj) {
          int pj = j + dj - 1;
          if (pj >= 0 && pj < 16) nn += ss2[lr * 16 + pj];
        }
      }
      float scale = 1.f / fmaxf(sqrtf(nn), 1e-6f);
      int lr = u / 3, dj = u % 3;
      int i2 = irow + lr - 1, pj = j + dj - 1;
      bool ok = (i2 >= 0 && i2 < 16 && pj >= 0 && pj < 16);
      size_t base = ((size_t)(b * 256 + irow * 16 + j)) * 288 + u * 32;
      #pragma unroll
      for (int q8 = 0; q8 < 4; ++q8) {
        short8 hv, lv;
        #pragma unroll
        for (int c = 0; c < 8; ++c) {
          float v = ok ? ph_s[(lr * 16 + pj) * 33 + q8 * 8 + c] * scale : 0.f;
          short hi = f2bf(v);
          hv[c] = hi;
          lv[c] = f2bf(v - bf2f(hi));
        }
        *(short8*)(Bh + base + q8 * 8) = hv;
        *(short8*)(Bl + base + q8 * 8) = lv;
      }
    }
  }
}

// ---------------- K3: scores via MFMA (bf16x3) + fused softmax -> attnp bf16 padded ----------------
__global__ __launch_bounds__(512) void k_sattn(const short* __restrict__ thetaPh,
                                               const short* __restrict__ thetaPl,
                                               const short* __restrict__ Bh,
                                               const short* __restrict__ Bl,
                                               short* __restrict__ attnp) {
  int mt = blockIdx.x;             // 0..31
  int b  = blockIdx.y;             // 0..7
  int tid = threadIdx.x;
  // zero attnp ring: 8320 short8-chunks per batch
  {
    int c = mt + 32 * tid;
    if (c < 8320) {
      int p = c >> 5, off = (c & 31) * 8;
      int r, cc; ring_px(p, r, cc);
      *(short8*)(attnp + ((size_t)(b * 66 + r) * 66 + cc) * 256 + off) = (short8)0;
    }
  }
  int w = tid >> 6, lane = tid & 63;
  int wm = w >> 2, wn = w & 3;
  int quad = lane >> 4, l16 = lane & 15;

  __shared__ __align__(16) short smem[32768];
  short* As = smem;
  short* Bs = smem + 4096;
  float* wred = (float*)(smem + 12288);

  f32x4 acc[4][4];
  #pragma unroll
  for (int i = 0; i < 4; ++i)
    #pragma unroll
    for (int j = 0; j < 4; ++j) acc[i][j] = (f32x4)0.f;

  int ar = w * 16 + (lane >> 2);
  int am = mt * 128 + ar;
  int aQy = am >> 6, aQx = am & 63;
  int achunk = (lane & 3) * 8;

  for (int kb = 0; kb < 27; ++kb) {
    int t = kb / 9, s = kb % 9;
    int di = s / 3, dj = s % 3;
    const short* Aarr = (t < 2) ? thetaPh : thetaPl;
    const short* Barr = (t == 1) ? Bl : Bh;
    __syncthreads();
    gload_lds16(Aarr + ((size_t)(b * 66 + aQy + di) * 66 + (aQx + dj)) * 32 + achunk,
                As + w * 512 + lane * 8);
    #pragma unroll
    for (int p = 0; p < 2; ++p) {
      int nl = w * 32 + p * 16 + (lane >> 2);
      gload_lds16(Barr + ((size_t)(b * 256 + nl)) * 288 + s * 32 + achunk,
                  Bs + w * 1024 + p * 512 + lane * 8);
    }
    __syncthreads();
    short8 af[4], bfr[4];
    #pragma unroll
    for (int i = 0; i < 4; ++i)
      af[i] = *(const short8*)(As + (wm * 64 + i * 16 + l16) * 32 + quad * 8);
    #pragma unroll
    for (int j = 0; j < 4; ++j)
      bfr[j] = *(const short8*)(Bs + (wn * 64 + j * 16 + l16) * 32 + quad * 8);
    #pragma unroll
    for (int i = 0; i < 4; ++i)
      #pragma unroll
      for (int j = 0; j < 4; ++j)
        acc[i][j] = __builtin_amdgcn_mfma_f32_16x16x32_bf16(af[i], bfr[j], acc[i][j], 0, 0, 0);
  }

  float rmax[4][4];
  #pragma unroll
  for (int i = 0; i < 4; ++i)
    #pragma unroll
    for (int reg = 0; reg < 4; ++reg) {
      float m = -1e30f;
      #pragma unroll
      for (int j = 0; j < 4; ++j) m = fmaxf(m, acc[i][j][reg]);
      #pragma unroll
      for (int off = 1; off < 16; off <<= 1) m = fmaxf(m, __shfl_xor(m, off));
      rmax[i][reg] = m;
    }
  if (l16 == 0) {
    #pragma unroll
    for (int i = 0; i < 4; ++i)
      #pragma unroll
      for (int reg = 0; reg < 4; ++reg)
        wred[(wm * 64 + i * 16 + quad * 4 + reg) * 4 + wn] = rmax[i][reg];
  }
  __syncthreads();
  #pragma unroll
  for (int i = 0; i < 4; ++i)
    #pragma unroll
    for (int reg = 0; reg < 4; ++reg) {
      int r = wm * 64 + i * 16 + quad * 4 + reg;
      rmax[i][reg] = fmaxf(fmaxf(wred[r * 4 + 0], wred[r * 4 + 1]),
                           fmaxf(wred[r * 4 + 2], wred[r * 4 + 3]));
    }
  __syncthreads();
  float rsum[4][4];
  #pragma unroll
  for (int i = 0; i < 4; ++i)
    #pragma unroll
    for (int reg = 0; reg < 4; ++reg) {
      float s = 0.f;
      #pragma unroll
      for (int j = 0; j < 4; ++j) {
        float e = expf((acc[i][j][reg] - rmax[i][reg]) * 10.f);
        acc[i][j][reg] = e;
        s += e;
      }
      #pragma unroll
      for (int off = 1; off < 16; off <<= 1) s += __shfl_xor(s, off);
      rsum[i][reg] = s;
    }
  if (l16 == 0) {
    #pragma unroll
    for (int i = 0; i < 4; ++i)
      #pragma unroll
      for (int reg = 0; reg < 4; ++reg)
        wred[(wm * 64 + i * 16 + quad * 4 + reg) * 4 + wn] = rsum[i][reg];
  }
  __syncthreads();
  #pragma unroll
  for (int i = 0; i < 4; ++i)
    #pragma unroll
    for (int reg = 0; reg < 4; ++reg) {
      int r = wm * 64 + i * 16 + quad * 4 + reg;
      float tot = wred[r * 4 + 0] + wred[r * 4 + 1] + wred[r * 4 + 2] + wred[r * 4 + 3];
      rsum[i][reg] = 1.f / tot;
    }
  __syncthreads();
  #pragma unroll
  for (int i = 0; i < 4; ++i)
    #pragma unroll
    for (int reg = 0; reg < 4; ++reg) {
      int r = wm * 64 + i * 16 + quad * 4 + reg;
      #pragma unroll
      for (int j = 0; j < 4; ++j)
        smem[r * 256 + wn * 64 + j * 16 + l16] = f2bf(acc[i][j][reg] * rsum[i][reg]);
    }
  __syncthreads();
  {
    int r2 = tid >> 2, c2 = (tid & 3) * 64;
    int m2 = mt * 128 + r2;
    int Qy = m2 >> 6, Qx = m2 & 63;
    short8* dst = (short8*)(attnp + ((size_t)(b * 66 + Qy + 1) * 66 + (Qx + 1)) * 256 + c2);
    #pragma unroll
    for (int q = 0; q < 8; ++q) dst[q] = *(const short8*)(smem + r2 * 256 + c2 + q * 8);
  }
}

// ---------------- K4a: gather g -> Bbf[b][n=(ry,rx,c)=1024][k=(dy,dx,i,j)=2304] bf16 ----------------
__global__ __launch_bounds__(256) void k_bgather(const float* __restrict__ g,
                                                 short* __restrict__ Bbf) {
  int r = blockIdx.x;              // 0..15 = (ry,rx)
  int bl = blockIdx.y;
  int ry = r >> 2, rx = r & 3;
  int t = threadIdx.x;
  int wv = t >> 6, l = t & 63;
  int jj = t >> 4, c4 = (t & 15) * 4;
  __shared__ short tile[256 * 66];
  const float* gb = g + (size_t)bl * 4096 * 64;
  for (int s = 0; s < 9; ++s) {
    int dy = s / 3, dx = s % 3;
    {
      int col = 4 * jj + rx + 4 * dx - 4;
      #pragma unroll
      for (int i2 = 0; i2 < 16; ++i2) {
        int row = 4 * i2 + ry + 4 * dy - 4;
        float4 v = make_float4(0.f, 0.f, 0.f, 0.f);
        if (row >= 0 && row < 64 && col >= 0 && col < 64)
          v = *(const float4*)(gb + (((size_t)row << 6) + col) * 64 + c4);
        int ij = i2 * 16 + jj;
        tile[ij * 66 + c4 + 0] = f2bf(v.x);
        tile[ij * 66 + c4 + 1] = f2bf(v.y);
        tile[ij * 66 + c4 + 2] = f2bf(v.z);
        tile[ij * 66 + c4 + 3] = f2bf(v.w);
      }
    }
    __syncthreads();
    #pragma unroll
    for (int cc = 0; cc < 16; ++cc) {
      int c = cc * 4 + wv;
      int n = r * 64 + c;
      unsigned* dstrow = (unsigned*)(Bbf + ((size_t)bl * 1024 + n) * 2304 + s * 256);
      #pragma unroll
      for (int half = 0; half < 2; ++half) {
        int ij0 = half * 128 + 2 * l;
        unsigned v = (unsigned)(unsigned short)tile[ij0 * 66 + c]
                   | ((unsigned)(unsigned short)tile[(ij0 + 1) * 66 + c] << 16);
        dstrow[half * 64 + l] = v;
      }
    }
    __syncthreads();
  }
}

// ---------------- K4b: deconv as MFMA GEMM, BK=64 (two 32-k chunks per barrier) ----------------
__global__ __launch_bounds__(256) void k_gemm(const short* __restrict__ attnp,
                                              const short* __restrict__ Bbf,
                                              float* __restrict__ out,
                                              int b0) {
  int mt = blockIdx.x;             // 0..31
  int nt = blockIdx.y;             // 0..7
  int bl = blockIdx.z;
  int b = b0 + bl;
  int tid = threadIdx.x;
  int wave = tid >> 6, lane = tid & 63;
  int wm = wave >> 1, wn = wave & 1;
  int quad = lane >> 4, l16 = lane & 15;

  __shared__ __align__(16) short As[8192];   // 2 chunks x 128x32
  __shared__ __align__(16) short Bs[8192];

  f32x4 acc[4][4];
  #pragma unroll
  for (int i = 0; i < 4; ++i)
    #pragma unroll
    for (int j = 0; j < 4; ++j) acc[i][j] = (f32x4)0.f;

  const short* Ab = attnp + (size_t)b * 66 * 66 * 256;
  const short* Bb = Bbf + (size_t)bl * 1024 * 2304 + (size_t)(nt * 128) * 2304;

  int larow = lane >> 2;
  int lakq8 = (lane & 3) * 8;

  for (int kb0 = 0; kb0 < 36; ++kb0) {
    __syncthreads();
    #pragma unroll
    for (int u = 0; u < 2; ++u) {
      int kb = kb0 * 2 + u;
      int s = kb >> 3;
      int dy = s / 3, dx = s % 3;
      int n0 = (kb & 7) * 32;
      #pragma unroll
      for (int t = 0; t < 2; ++t) {
        int rr = wave * 32 + t * 16 + larow;
        int m = mt * 128 + rr;
        int hh = (m >> 6) + 2 - dy;
        int wwp = (m & 63) + 2 - dx;
        gload_lds16(Ab + ((size_t)(hh * 66 + wwp) << 8) + n0 + lakq8,
                    As + u * 4096 + wave * 1024 + t * 512 + lane * 8);
        gload_lds16(Bb + (size_t)rr * 2304 + kb * 32 + lakq8,
                    Bs + u * 4096 + wave * 1024 + t * 512 + lane * 8);
      }
    }
    __syncthreads();
    #pragma unroll
    for (int u = 0; u < 2; ++u) {
      short8 af[4], bfr[4];
      #pragma unroll
      for (int i = 0; i < 4; ++i)
        af[i] = *(const short8*)(As + u * 4096 + (wm * 64 + i * 16 + l16) * 32 + quad * 8);
      #pragma unroll
      for (int j = 0; j < 4; ++j)
        bfr[j] = *(const short8*)(Bs + u * 4096 + (wn * 64 + j * 16 + l16) * 32 + quad * 8);
      #pragma unroll
      for (int i = 0; i < 4; ++i)
        #pragma unroll
        for (int j = 0; j < 4; ++j)
          acc[i][j] = __builtin_amdgcn_mfma_f32_16x16x32_bf16(af[i], bfr[j], acc[i][j], 0, 0, 0);
    }
  }

  const float inv6 = 1.f / 6.f;
  #pragma unroll
  for (int i = 0; i < 4; ++i) {
    int mbase = mt * 128 + wm * 64 + i * 16 + quad * 4;
    #pragma unroll
    for (int j = 0; j < 4; ++j) {
      int n = nt * 128 + wn * 64 + j * 16 + l16;
      int r = n >> 6; int c = n & 63;
      int ry = r >> 2, rx = r & 3;
      #pragma unroll
      for (int reg = 0; reg < 4; ++reg) {
        int m = mbase + reg;
        int Qy = m >> 6, Qx = m & 63;
        out[(((size_t)b * 256 + 4 * Qy + ry) * 256 + (4 * Qx + rx)) * 64 + c]
            = acc[i][j][reg] * inv6;
      }
    }
  }
}

extern "C" void kernel_launch(void* const* d_in, const int* in_sizes, int n_in,
                              void* d_out, int out_size, void* d_ws, size_t ws_size,
                              hipStream_t stream) {
  const float* x           = (const float*)d_in[0];
  const float* theta_w     = (const float*)d_in[1];
  const float* theta_b     = (const float*)d_in[2];
  const float* theta_alpha = (const float*)d_in[3];
  const float* phi_w       = (const float*)d_in[4];
  const float* phi_b       = (const float*)d_in[5];
  const float* phi_alpha   = (const float*)d_in[6];
  const float* g_w         = (const float*)d_in[7];
  const float* g_b         = (const float*)d_in[8];
  const float* g_alpha     = (const float*)d_in[9];
  float* out = (float*)d_out;

  char* w = (char*)d_ws;
  size_t off = 0;
  auto alloc = [&](size_t bytes) { void* p = w + off; off += (bytes + 255) & ~255ull; return p; };
  float* g       = (float*)alloc(8ull * 4096 * 64 * 4);       // 8 MB
  size_t thp_bytes = 8ull * 66 * 66 * 32 * 2;                 // 2.23 MB
  short* thetaPh = (short*)alloc(thp_bytes);
  short* thetaPl = (short*)alloc(thp_bytes);
  short* Bh      = (short*)alloc(8ull * 256 * 288 * 2);       // 1.18 MB
  short* Bl      = (short*)alloc(8ull * 256 * 288 * 2);
  size_t attnp_bytes = 8ull * 66 * 66 * 256 * 2;              // 17.8 MB
  short* attnp   = (short*)alloc(attnp_bytes);
  size_t bbf_full = 8ull * 1024 * 2304 * 2;                   // 37.7 MB
  bool full = (off + bbf_full) <= ws_size;
  short* Bbf = (short*)alloc(full ? bbf_full : bbf_full / 8);

  hipLaunchKernelGGL(k_pre, dim3(256 + 128), dim3(256), 0, stream,
                     x, theta_w, theta_b, theta_alpha, phi_w, phi_b, phi_alpha,
                     g_w, g_b, g_alpha, thetaPh, thetaPl, g, Bh, Bl);
  if (full) {
    hipLaunchKernelGGL(k_bgather, dim3(16, BB), dim3(256), 0, stream, g, Bbf);
    hipLaunchKernelGGL(k_sattn, dim3(32, BB), dim3(512), 0, stream,
                       thetaPh, thetaPl, Bh, Bl, attnp);
    hipLaunchKernelGGL(k_gemm, dim3(32, 8, BB), dim3(256), 0, stream, attnp, Bbf, out, 0);
  } else {
    hipLaunchKernelGGL(k_sattn, dim3(32, BB), dim3(512), 0, stream,
                       thetaPh, thetaPl, Bh, Bl, attnp);
    for (int b = 0; b < BB; ++b) {
      hipLaunchKernelGGL(k_bgather, dim3(16, 1), dim3(256), 0, stream,
                         g + (size_t)b * 4096 * 64, Bbf);
      hipLaunchKernelGGL(k_gemm, dim3(32, 8, 1), dim3(256), 0, stream, attnp, Bbf, out, b);
    }
  }
}